// Round 13
// baseline (4339.168 us; speedup 1.0000x reference)
//
#include <hip/hip_runtime.h>
#include <hip/hip_bf16.h>
#include <cstdint>

// ============================================================================
// Neural-ODE actor: y0=[x,0...]; 4 RK4(3/8) steps, f = 72->256->256->72 MLP.
// Fully fused: one block owns 96 samples for all 16 f-evals. Split-bf16 MFMA
// (hi+lo bf16 per fp32; C = Ah*Bh + Al*Bh + Ah*Bl) ~ fp32 accuracy at MFMA
// rate. Weights pre-packed into MFMA B-frag order in d_ws (L2-resident).
// Activations in LDS as (hi|lo<<16) u32 pairs, XOR-swizzled.
//
// R5: VGPR budget 128 -> spill-bound (WRITE 1.35GB). R6: St-merge -> 325MB,
// 3.63ms, but VGPR stayed 128: __launch_bounds__(512,2) => 2 blocks/CU =>
// 4 waves/EU min => 128-reg target, overriding amdgpu_waves_per_eu.
// R7: drop __launch_bounds__; native attributes only:
//   amdgpu_flat_work_group_size(512,512) + amdgpu_waves_per_eu(2,2)
//   => 256-VGPR budget == LDS-capped occupancy (134.5KB -> 1 block/CU).
// R11 hedge (attribution-safe): B-frag loads moved inside the tt-loop and
// consumed immediately -> transient B-frag liveness 8 regs (was 32). Peak
// live ~144 regs: fits 256 outright; at 128 only ~16 spill (vs ~80 in R6).
// Discriminator stays VGPR_Count (reorder can't change it at a 256 budget).
// ============================================================================

#define IN_DIM 15
#define CD     36
#define STATE  72
#define KP1    96      // K of GEMM1 padded to 3*32 (sZ width)
#define HID    256
#define NP3    128     // N of GEMM3 padded to 8*16
#define MT     96      // samples per block
#define NTHR   512

typedef short    bf16x8 __attribute__((ext_vector_type(8)));
typedef float    f32x4  __attribute__((ext_vector_type(4)));
typedef uint32_t u32;
typedef u32      u32x4  __attribute__((ext_vector_type(4)));

// ws layout, int4 (16B) units: frag index = (s*NT + t)*64 + lane
#define W1H 0
#define W1L 3072
#define W2H 6144
#define W2L 14336
#define W3H 22528
#define W3L 26624
// total 30720 int4 = 480 KB of d_ws

// split fp32 -> (bf16 hi | bf16 lo << 16), RNE both; hi+lo == v to ~2^-17 rel
__device__ __forceinline__ u32 pack_split(float v) {
    u32 u  = __builtin_bit_cast(u32, v);
    u32 h  = (u + 0x7FFFu + ((u >> 16) & 1u)) >> 16;
    float hf = __builtin_bit_cast(float, h << 16);
    float l  = v - hf;                       // exact 2-term split
    u32 lu = __builtin_bit_cast(u32, l);
    u32 lo = (lu + 0x7FFFu + ((lu >> 16) & 1u)) >> 16;
    return h | (lo << 16);
}
__device__ __forceinline__ float unpack_pair(u32 p) {
    return __builtin_bit_cast(float, p << 16) +
           __builtin_bit_cast(float, p & 0xFFFF0000u);
}

// ---------------------------------------------------------------------------
// Prep: pack W1/W2/W3 (hi,lo) into MFMA B-frag order, zero-padding K/N.
// k-map kappa(g,j): j<4 -> 32s + 4g + j ; j>=4 -> 32s + 16 + 4g + (j-4).
// Any bijection is exact as long as A-reads use the same one (they do).
// ---------------------------------------------------------------------------
__global__ void prep_pack(const float* __restrict__ W1, const float* __restrict__ W2,
                          const float* __restrict__ W3, int4* __restrict__ ws) {
    int tid = blockIdx.x * 256 + threadIdx.x;
    if (tid >= 15360) return;
    const float* W; int NT, Kr, Nr, lidx, oh, ol;
    if (tid < 3072)       { W = W1; NT = 16; Kr = 72;  Nr = 256; lidx = tid;         oh = W1H; ol = W1L; }
    else if (tid < 11264) { W = W2; NT = 16; Kr = 256; Nr = 256; lidx = tid - 3072;  oh = W2H; ol = W2L; }
    else                  { W = W3; NT = 8;  Kr = 256; Nr = 72;  lidx = tid - 11264; oh = W3H; ol = W3L; }
    int lane = lidx & 63;
    int t    = (lidx >> 6) % NT;
    int s    = (lidx >> 6) / NT;
    int g = lane >> 4, c = lane & 15;
    int nn = t * 16 + c;
    u32 hw[4], lw[4];
    #pragma unroll
    for (int p = 0; p < 4; ++p) {
        u32 hh = 0, ll = 0;
        #pragma unroll
        for (int q = 0; q < 2; ++q) {
            int j  = 2 * p + q;
            int kk = s * 32 + ((j < 4) ? (g * 4 + j) : (16 + g * 4 + (j - 4)));
            float w = 0.f;
            if (kk < Kr && nn < Nr) w = W[kk * Nr + nn];
            u32 pr = pack_split(w);
            hh |= (pr & 0xFFFFu) << (16 * q);
            ll |= (pr >> 16)     << (16 * q);
        }
        hw[p] = hh; lw[p] = ll;
    }
    u32x4 H = {hw[0], hw[1], hw[2], hw[3]};
    u32x4 L = {lw[0], lw[1], lw[2], lw[3]};
    ws[oh + lidx] = __builtin_bit_cast(int4, H);
    ws[ol + lidx] = __builtin_bit_cast(int4, L);
}

// ---------------------------------------------------------------------------
// A-fragment (hi,lo) from interleaved-pair LDS buffer.
// Lane reads its A row (lane&15); k-elems j0..3 at colbytes cb..cb+15,
// j4..7 at cb+64.. (matches kappa; cb = s*128 + (lane>>4)*16). XOR swizzle
// (row&7)<<4 applied to the full byte column offset, matching the writers.
// v_perm splits each (hi|lo<<16) u32 pair into hi-plane / lo-plane bf16x8.
// ---------------------------------------------------------------------------
__device__ __forceinline__ void load_afrag(const u32* Abuf, int rowb_u32, int row,
                                           int cb, bf16x8& ah, bf16x8& al) {
    const char* base = (const char*)(Abuf + row * rowb_u32);
    int sw = (row & 7) << 4;
    int4 v03 = *(const int4*)(base + (cb ^ sw));
    int4 v47 = *(const int4*)(base + ((cb + 64) ^ sw));
    u32 h0 = __builtin_amdgcn_perm((u32)v03.y, (u32)v03.x, 0x05040100u);
    u32 l0 = __builtin_amdgcn_perm((u32)v03.y, (u32)v03.x, 0x07060302u);
    u32 h1 = __builtin_amdgcn_perm((u32)v03.w, (u32)v03.z, 0x05040100u);
    u32 l1 = __builtin_amdgcn_perm((u32)v03.w, (u32)v03.z, 0x07060302u);
    u32 h2 = __builtin_amdgcn_perm((u32)v47.y, (u32)v47.x, 0x05040100u);
    u32 l2 = __builtin_amdgcn_perm((u32)v47.y, (u32)v47.x, 0x07060302u);
    u32 h3 = __builtin_amdgcn_perm((u32)v47.w, (u32)v47.z, 0x05040100u);
    u32 l3 = __builtin_amdgcn_perm((u32)v47.w, (u32)v47.z, 0x07060302u);
    u32x4 hv = {h0, h1, h2, h3}, lv = {l0, l1, l2, l3};
    ah = __builtin_bit_cast(bf16x8, hv);
    al = __builtin_bit_cast(bf16x8, lv);
}

// One layer GEMM: A = [96 x 32*NS] pairs in LDS, B = frag-packed global.
// Wave (wm,wn): m-tiles {wm*48 + mm*16}, n-tiles {wn*TT + tt}.
// 3 MFMAs per (mm,tt,s): Ah*Bh + Al*Bh + Ah*Bl (split-bf16).
// B-frags loaded per-tt and consumed immediately (transient 8 regs, not 32):
// at a 256-reg budget the scheduler hoists them; at 128 it avoids spill.
template<int NS, int NT, int TT, int ROWB>
__device__ __forceinline__ void gemm_layer(const u32* Abuf, const int4* ph, const int4* pl,
                                           const float* bias, int wm, int wn, int lane,
                                           f32x4 (&acc)[3][TT]) {
    const int lc = lane & 15, lr = lane >> 4;
    #pragma unroll
    for (int mm = 0; mm < 3; ++mm)
        #pragma unroll
        for (int tt = 0; tt < TT; ++tt) {
            float bv = bias[(wn * TT + tt) * 16 + lc];
            acc[mm][tt] = (f32x4){bv, bv, bv, bv};
        }
    #pragma unroll 2
    for (int s = 0; s < NS; ++s) {
        bf16x8 ah[3], al[3];
        #pragma unroll
        for (int mm = 0; mm < 3; ++mm)
            load_afrag(Abuf, ROWB / 4, wm * 48 + mm * 16 + lc, s * 128 + lr * 16, ah[mm], al[mm]);
        #pragma unroll
        for (int tt = 0; tt < TT; ++tt) {
            int fi = (s * NT + wn * TT + tt) * 64 + lane;
            bf16x8 bhv = __builtin_bit_cast(bf16x8, ph[fi]);
            bf16x8 blv = __builtin_bit_cast(bf16x8, pl[fi]);
            #pragma unroll
            for (int mm = 0; mm < 3; ++mm) {
                acc[mm][tt] = __builtin_amdgcn_mfma_f32_16x16x32_bf16(ah[mm], bhv, acc[mm][tt], 0, 0, 0);
                acc[mm][tt] = __builtin_amdgcn_mfma_f32_16x16x32_bf16(al[mm], bhv, acc[mm][tt], 0, 0, 0);
                acc[mm][tt] = __builtin_amdgcn_mfma_f32_16x16x32_bf16(ah[mm], blv, acc[mm][tt], 0, 0, 0);
            }
        }
    }
}

// ---------------------------------------------------------------------------
// Fused ODE kernel. 512 thr (8 waves, 2x4 wave grid), 96 samples/block.
// LDS 134.5 KB -> 1 block/CU, 2 waves/SIMD. Occupancy contract expressed
// ONLY via native attributes (launch_bounds removed — R6 showed it forced a
// 128-VGPR budget): flat_work_group_size pins block size; waves_per_eu(2,2)
// sets the 256-VGPR cap that matches LDS-capped occupancy -> no spill.
// ---------------------------------------------------------------------------
__attribute__((amdgpu_flat_work_group_size(NTHR, NTHR), amdgpu_waves_per_eu(2, 2)))
__global__ void ode_fused(
    const float* __restrict__ x, const float* __restrict__ b1,
    const float* __restrict__ b2, const float* __restrict__ b3,
    const int4* __restrict__ ws, float* __restrict__ out, int Bn) {

    __shared__ u32 sH[MT * HID];   // 96 KB: h1/h2 (hi|lo pairs, swizzled)
    __shared__ u32 sZ[MT * KP1];   // 36 KB: z (cols 72..95 stay 0)
    __shared__ float sB1[HID], sB2[HID], sB3[NP3];

    const int tid  = threadIdx.x;
    const int lane = tid & 63, wv = tid >> 6;
    const int wm = wv >> 2, wn = wv & 3;
    const int lr = lane >> 4, lc = lane & 15;
    const int m0 = blockIdx.x * MT;

    for (int i = tid; i < HID; i += NTHR) { sB1[i] = b1[i]; sB2[i] = b2[i]; }
    for (int i = tid; i < NP3; i += NTHR) {
        float v = 0.f;
        if (i < STATE) v = b3[i];
        sB3[i] = v;
    }

    // --- init: Y = y0 = [x, 0...]; sZ = split(Y). Ownership == G3 C-map.
    float Y[3][2][4];
    #pragma unroll
    for (int mm = 0; mm < 3; ++mm)
        #pragma unroll
        for (int tt = 0; tt < 2; ++tt) {
            int d = (wn * 2 + tt) * 16 + lc;
            #pragma unroll
            for (int r = 0; r < 4; ++r) {
                int row = wm * 48 + mm * 16 + lr * 4 + r;
                int m   = m0 + row;
                float v = 0.f;
                if (d < IN_DIM && m < Bn) v = x[m * IN_DIM + d];
                Y[mm][tt][r] = v;
                if (d < KP1) sZ[row * KP1 + (d ^ ((row & 7) << 2))] = pack_split(v);
            }
        }
    __syncthreads();

    // St: z2 while live (j=1->j=2), then the RK4 partial Pa (j=2->j=3).
    float St[3][2][4];

    #pragma unroll 1
    for (int step = 0; step < 4; ++step) {
        float dt = (step == 3) ? 0.1f : 0.3f;
        #pragma unroll 1
        for (int j = 0; j < 4; ++j) {
            // ---- GEMM1: h1 = relu(z @ W1 + b1), K=96(pad), N=256
            f32x4 acc[3][4];
            gemm_layer<3, 16, 4, KP1 * 4>(sZ, ws + W1H, ws + W1L, sB1, wm, wn, lane, acc);
            #pragma unroll
            for (int mm = 0; mm < 3; ++mm)
                #pragma unroll
                for (int tt = 0; tt < 4; ++tt)
                    #pragma unroll
                    for (int r = 0; r < 4; ++r) {
                        int row = wm * 48 + mm * 16 + lr * 4 + r;
                        int col = (wn * 4 + tt) * 16 + lc;
                        float v = fmaxf(acc[mm][tt][r], 0.f);
                        sH[row * HID + (col ^ ((row & 7) << 2))] = pack_split(v);
                    }
            __syncthreads();

            // ---- GEMM2: h2 = relu(h1 @ W2 + b2), K=256, N=256
            gemm_layer<8, 16, 4, HID * 4>(sH, ws + W2H, ws + W2L, sB2, wm, wn, lane, acc);
            __syncthreads();                      // all h1 reads done
            #pragma unroll
            for (int mm = 0; mm < 3; ++mm)
                #pragma unroll
                for (int tt = 0; tt < 4; ++tt)
                    #pragma unroll
                    for (int r = 0; r < 4; ++r) {
                        int row = wm * 48 + mm * 16 + lr * 4 + r;
                        int col = (wn * 4 + tt) * 16 + lc;
                        float v = fmaxf(acc[mm][tt][r], 0.f);
                        sH[row * HID + (col ^ ((row & 7) << 2))] = pack_split(v);
                    }
            __syncthreads();

            // ---- GEMM3: k = h2 @ W3 + b3, K=256, N=128(pad; cols>=72 all 0)
            f32x4 acc3[3][2];
            gemm_layer<8, 8, 2, HID * 4>(sH, ws + W3H, ws + W3L, sB3, wm, wn, lane, acc3);

            // ---- RK4 owner update (each thread owns its C elements)
            #pragma unroll
            for (int mm = 0; mm < 3; ++mm)
                #pragma unroll
                for (int tt = 0; tt < 2; ++tt) {
                    int d = (wn * 2 + tt) * 16 + lc;
                    #pragma unroll
                    for (int r = 0; r < 4; ++r) {
                        int row = wm * 48 + mm * 16 + lr * 4 + r;
                        int zi  = row * KP1 + (d ^ ((row & 7) << 2));
                        float C = acc3[mm][tt][r];
                        float y = Y[mm][tt][r];
                        if (j == 0) {
                            float z = y + (dt * (1.f / 3.f)) * C;
                            if (d < KP1) sZ[zi] = pack_split(z);
                        } else if (j == 1) {
                            float z2 = 0.f;
                            if (d < KP1) z2 = unpack_pair(sZ[zi]);
                            St[mm][tt][r] = z2;
                            float z = 2.f * y - z2 + dt * C;
                            if (d < KP1) sZ[zi] = pack_split(z);
                        } else if (j == 2) {
                            float z3 = 0.f;
                            if (d < KP1) z3 = unpack_pair(sZ[zi]);
                            float z2 = St[mm][tt][r];
                            float z = 2.f * z2 - z3 + dt * C;
                            if (d < KP1) sZ[zi] = pack_split(z);
                            St[mm][tt][r] = 6.f * z2 + 3.f * z3 - 9.f * y + 3.f * dt * C;
                        } else {
                            float yn = y + (St[mm][tt][r] + dt * C) * 0.125f;
                            Y[mm][tt][r] = yn;
                            if (step < 3 && d < KP1) sZ[zi] = pack_split(yn);
                        }
                    }
                }
            __syncthreads();
        }
    }

    // ---- outputs: action = clip(y[15:27],±1), force = clip(y[27:36],±2)
    #pragma unroll
    for (int mm = 0; mm < 3; ++mm)
        #pragma unroll
        for (int tt = 0; tt < 2; ++tt) {
            int d = (wn * 2 + tt) * 16 + lc;
            #pragma unroll
            for (int r = 0; r < 4; ++r) {
                int m = m0 + wm * 48 + mm * 16 + lr * 4 + r;
                if (m >= Bn) continue;
                float v = Y[mm][tt][r];
                if (d >= IN_DIM && d < IN_DIM + 12)
                    out[m * 12 + (d - IN_DIM)] = fminf(fmaxf(v, -1.f), 1.f);
                else if (d >= IN_DIM + 12 && d < CD)
                    out[Bn * 12 + m * 9 + (d - IN_DIM - 12)] = fminf(fmaxf(v, -2.f), 2.f);
            }
        }
}

extern "C" void kernel_launch(void* const* d_in, const int* in_sizes, int n_in,
                              void* d_out, int out_size, void* d_ws, size_t ws_size,
                              hipStream_t stream) {
    const float* x  = (const float*)d_in[0];
    const float* W1 = (const float*)d_in[1];
    const float* b1 = (const float*)d_in[2];
    const float* W2 = (const float*)d_in[3];
    const float* b2 = (const float*)d_in[4];
    const float* W3 = (const float*)d_in[5];
    const float* b3 = (const float*)d_in[6];
    int Bn = in_sizes[0] / IN_DIM;
    int4* ws = (int4*)d_ws;   // needs 480 KB

    hipLaunchKernelGGL(prep_pack, dim3(60), dim3(256), 0, stream, W1, W2, W3, ws);
    int grid = (Bn + MT - 1) / MT;
    hipLaunchKernelGGL(ode_fused, dim3(grid), dim3(NTHR), 0, stream,
                       x, b1, b2, b3, ws, (float*)d_out, Bn);
}

// Round 14
// 2485.958 us; speedup vs baseline: 1.7455x; 1.7455x over previous
//
#include <hip/hip_runtime.h>
#include <hip/hip_bf16.h>
#include <cstdint>

// ============================================================================
// Neural-ODE actor: y0=[x,0...]; 4 RK4(3/8) steps, f = 72->256->256->72 MLP.
// Fully fused; split-bf16 MFMA (hi+lo bf16 per fp32; Ah*Bh + Al*Bh + Ah*Bl)
// ~ fp32 accuracy at MFMA rate. Weights pre-packed in MFMA B-frag order in
// d_ws (L2-resident). Activations in LDS as (hi|lo<<16) pairs, XOR-swizzled.
//
// History: R5 spill-bound at VGPR=128 (WRITE 1.35GB). R6 St-merge -> 325MB,
// 3.63ms. R7/R11 native attrs (flat_work_group_size + waves_per_eu(2,2)):
// VGPR STILL 128 (R13) -> attribute path falsified; per-tt B-loads under a
// spilling allocation serialized weight loads (4.40ms).
// R13 structural redesign — design FOR the 128-reg budget:
//   MT 96->48, wave grid 2x4 -> 1x8 (wave owns 3 m-tiles x its n-slice):
//   peak live ~110 regs (acc 24 + A 24 + B 16 + Y 12 + St 12 + addr) -> no
//   spill at 128. LDS 134.5 -> 68.5 KB -> 2 blocks/CU -> 16 waves/CU
//   (4 waves/EU), matching the 128-reg occupancy. 1x8 grid also removes the
//   wm-duplication of B-frag reads (block reads each weight byte once/eval).
// ============================================================================

#define IN_DIM 15
#define CD     36
#define STATE  72
#define KP1    96      // K of GEMM1 padded to 3*32 (sZ width)
#define HID    256
#define NP3    128     // N of GEMM3 padded to 8*16
#define MT     48      // samples per block
#define NTHR   512

typedef short    bf16x8 __attribute__((ext_vector_type(8)));
typedef float    f32x4  __attribute__((ext_vector_type(4)));
typedef uint32_t u32;
typedef u32      u32x4  __attribute__((ext_vector_type(4)));

// ws layout, int4 (16B) units: frag index = (s*NT + t)*64 + lane  (unchanged)
#define W1H 0
#define W1L 3072
#define W2H 6144
#define W2L 14336
#define W3H 22528
#define W3L 26624
// total 30720 int4 = 480 KB of d_ws

// split fp32 -> (bf16 hi | bf16 lo << 16), RNE both; hi+lo == v to ~2^-17 rel
__device__ __forceinline__ u32 pack_split(float v) {
    u32 u  = __builtin_bit_cast(u32, v);
    u32 h  = (u + 0x7FFFu + ((u >> 16) & 1u)) >> 16;
    float hf = __builtin_bit_cast(float, h << 16);
    float l  = v - hf;                       // exact 2-term split
    u32 lu = __builtin_bit_cast(u32, l);
    u32 lo = (lu + 0x7FFFu + ((lu >> 16) & 1u)) >> 16;
    return h | (lo << 16);
}
__device__ __forceinline__ float unpack_pair(u32 p) {
    return __builtin_bit_cast(float, p << 16) +
           __builtin_bit_cast(float, p & 0xFFFF0000u);
}

// ---------------------------------------------------------------------------
// Prep: pack W1/W2/W3 (hi,lo) into MFMA B-frag order, zero-padding K/N.
// k-map kappa(g,j): j<4 -> 32s + 4g + j ; j>=4 -> 32s + 16 + 4g + (j-4).
// Any bijection is exact as long as A-reads use the same one (they do).
// ---------------------------------------------------------------------------
__global__ void prep_pack(const float* __restrict__ W1, const float* __restrict__ W2,
                          const float* __restrict__ W3, int4* __restrict__ ws) {
    int tid = blockIdx.x * 256 + threadIdx.x;
    if (tid >= 15360) return;
    const float* W; int NT, Kr, Nr, lidx, oh, ol;
    if (tid < 3072)       { W = W1; NT = 16; Kr = 72;  Nr = 256; lidx = tid;         oh = W1H; ol = W1L; }
    else if (tid < 11264) { W = W2; NT = 16; Kr = 256; Nr = 256; lidx = tid - 3072;  oh = W2H; ol = W2L; }
    else                  { W = W3; NT = 8;  Kr = 256; Nr = 72;  lidx = tid - 11264; oh = W3H; ol = W3L; }
    int lane = lidx & 63;
    int t    = (lidx >> 6) % NT;
    int s    = (lidx >> 6) / NT;
    int g = lane >> 4, c = lane & 15;
    int nn = t * 16 + c;
    u32 hw[4], lw[4];
    #pragma unroll
    for (int p = 0; p < 4; ++p) {
        u32 hh = 0, ll = 0;
        #pragma unroll
        for (int q = 0; q < 2; ++q) {
            int j  = 2 * p + q;
            int kk = s * 32 + ((j < 4) ? (g * 4 + j) : (16 + g * 4 + (j - 4)));
            float w = 0.f;
            if (kk < Kr && nn < Nr) w = W[kk * Nr + nn];
            u32 pr = pack_split(w);
            hh |= (pr & 0xFFFFu) << (16 * q);
            ll |= (pr >> 16)     << (16 * q);
        }
        hw[p] = hh; lw[p] = ll;
    }
    u32x4 H = {hw[0], hw[1], hw[2], hw[3]};
    u32x4 L = {lw[0], lw[1], lw[2], lw[3]};
    ws[oh + lidx] = __builtin_bit_cast(int4, H);
    ws[ol + lidx] = __builtin_bit_cast(int4, L);
}

// ---------------------------------------------------------------------------
// A-fragment (hi,lo) from interleaved-pair LDS buffer.
// Lane reads A row (mm*16 + lane&15); k-elems j0..3 at colbytes cb..cb+15,
// j4..7 at cb+64.. (matches kappa; cb = s*128 + (lane>>4)*16). XOR swizzle
// (row&7)<<4 on the byte column offset, matching the writers. v_perm splits
// each (hi|lo<<16) u32 pair into hi-plane / lo-plane bf16x8.
// ---------------------------------------------------------------------------
__device__ __forceinline__ void load_afrag(const u32* Abuf, int rowb_u32, int row,
                                           int cb, bf16x8& ah, bf16x8& al) {
    const char* base = (const char*)(Abuf + row * rowb_u32);
    int sw = (row & 7) << 4;
    int4 v03 = *(const int4*)(base + (cb ^ sw));
    int4 v47 = *(const int4*)(base + ((cb + 64) ^ sw));
    u32 h0 = __builtin_amdgcn_perm((u32)v03.y, (u32)v03.x, 0x05040100u);
    u32 l0 = __builtin_amdgcn_perm((u32)v03.y, (u32)v03.x, 0x07060302u);
    u32 h1 = __builtin_amdgcn_perm((u32)v03.w, (u32)v03.z, 0x05040100u);
    u32 l1 = __builtin_amdgcn_perm((u32)v03.w, (u32)v03.z, 0x07060302u);
    u32 h2 = __builtin_amdgcn_perm((u32)v47.y, (u32)v47.x, 0x05040100u);
    u32 l2 = __builtin_amdgcn_perm((u32)v47.y, (u32)v47.x, 0x07060302u);
    u32 h3 = __builtin_amdgcn_perm((u32)v47.w, (u32)v47.z, 0x05040100u);
    u32 l3 = __builtin_amdgcn_perm((u32)v47.w, (u32)v47.z, 0x07060302u);
    u32x4 hv = {h0, h1, h2, h3}, lv = {l0, l1, l2, l3};
    ah = __builtin_bit_cast(bf16x8, hv);
    al = __builtin_bit_cast(bf16x8, lv);
}

// One layer GEMM: A = [48 x 32*NS] pairs in LDS, B = frag-packed global.
// 1x8 wave grid: wave wn owns n-tiles {wn*TT + tt}, all 3 m-tiles.
// 3 MFMAs per (mm,tt,s): Ah*Bh + Al*Bh + Ah*Bl (split-bf16).
template<int NS, int NT, int TT, int ROWB>
__device__ __forceinline__ void gemm_layer(const u32* Abuf, const int4* ph, const int4* pl,
                                           const float* bias, int wn, int lane,
                                           f32x4 (&acc)[3][TT]) {
    const int lc = lane & 15, lr = lane >> 4;
    #pragma unroll
    for (int mm = 0; mm < 3; ++mm)
        #pragma unroll
        for (int tt = 0; tt < TT; ++tt) {
            float bv = bias[(wn * TT + tt) * 16 + lc];
            acc[mm][tt] = (f32x4){bv, bv, bv, bv};
        }
    #pragma unroll 2
    for (int s = 0; s < NS; ++s) {
        int4 bh[TT], bl[TT];
        #pragma unroll
        for (int tt = 0; tt < TT; ++tt) {
            int fi = (s * NT + wn * TT + tt) * 64 + lane;
            bh[tt] = ph[fi]; bl[tt] = pl[fi];
        }
        bf16x8 ah[3], al[3];
        #pragma unroll
        for (int mm = 0; mm < 3; ++mm)
            load_afrag(Abuf, ROWB / 4, mm * 16 + lc, s * 128 + lr * 16, ah[mm], al[mm]);
        #pragma unroll
        for (int tt = 0; tt < TT; ++tt) {
            bf16x8 bhv = __builtin_bit_cast(bf16x8, bh[tt]);
            bf16x8 blv = __builtin_bit_cast(bf16x8, bl[tt]);
            #pragma unroll
            for (int mm = 0; mm < 3; ++mm) {
                acc[mm][tt] = __builtin_amdgcn_mfma_f32_16x16x32_bf16(ah[mm], bhv, acc[mm][tt], 0, 0, 0);
                acc[mm][tt] = __builtin_amdgcn_mfma_f32_16x16x32_bf16(al[mm], bhv, acc[mm][tt], 0, 0, 0);
                acc[mm][tt] = __builtin_amdgcn_mfma_f32_16x16x32_bf16(ah[mm], blv, acc[mm][tt], 0, 0, 0);
            }
        }
    }
}

// ---------------------------------------------------------------------------
// Fused ODE kernel. 512 thr (8 waves, 1x8 wave grid), 48 samples/block.
// LDS 68.5 KB -> 2 blocks/CU -> 16 waves/CU (4 waves/EU) == the compiler's
// 128-VGPR budget. Peak live ~110 regs -> no spill. waves_per_eu(4) makes
// the contract explicit.
// ---------------------------------------------------------------------------
__attribute__((amdgpu_flat_work_group_size(NTHR, NTHR), amdgpu_waves_per_eu(4)))
__global__ void ode_fused(
    const float* __restrict__ x, const float* __restrict__ b1,
    const float* __restrict__ b2, const float* __restrict__ b3,
    const int4* __restrict__ ws, float* __restrict__ out, int Bn) {

    __shared__ u32 sH[MT * HID];   // 48 KB: h1/h2 (hi|lo pairs, swizzled)
    __shared__ u32 sZ[MT * KP1];   // 18 KB: z (cols 72..95 stay 0)
    __shared__ float sB1[HID], sB2[HID], sB3[NP3];

    const int tid  = threadIdx.x;
    const int lane = tid & 63;
    const int wn   = tid >> 6;           // 0..7
    const int lr = lane >> 4, lc = lane & 15;
    const int d  = wn * 16 + lc;         // owned feature column (0..127)
    const int m0 = blockIdx.x * MT;

    for (int i = tid; i < HID; i += NTHR) { sB1[i] = b1[i]; sB2[i] = b2[i]; }
    if (tid < NP3) sB3[tid] = (tid < STATE) ? b3[tid] : 0.f;

    // --- init: Y = y0 = [x, 0...]; sZ = split(Y). Ownership == G3 C-map.
    float Y[3][4];
    #pragma unroll
    for (int mm = 0; mm < 3; ++mm)
        #pragma unroll
        for (int r = 0; r < 4; ++r) {
            int row = mm * 16 + lr * 4 + r;
            int m   = m0 + row;
            float v = 0.f;
            if (d < IN_DIM && m < Bn) v = x[m * IN_DIM + d];
            Y[mm][r] = v;
            if (d < KP1) sZ[row * KP1 + (d ^ ((row & 7) << 2))] = pack_split(v);
        }
    __syncthreads();

    // St: z2 while live (j=1->j=2), then the RK4 partial Pa (j=2->j=3).
    float St[3][4];

    #pragma unroll 1
    for (int step = 0; step < 4; ++step) {
        float dt = (step == 3) ? 0.1f : 0.3f;
        #pragma unroll 1
        for (int j = 0; j < 4; ++j) {
            // ---- GEMM1: h1 = relu(z @ W1 + b1), K=96(pad), N=256
            f32x4 acc[3][2];
            gemm_layer<3, 16, 2, KP1 * 4>(sZ, ws + W1H, ws + W1L, sB1, wn, lane, acc);
            #pragma unroll
            for (int mm = 0; mm < 3; ++mm)
                #pragma unroll
                for (int tt = 0; tt < 2; ++tt)
                    #pragma unroll
                    for (int r = 0; r < 4; ++r) {
                        int row = mm * 16 + lr * 4 + r;
                        int col = (wn * 2 + tt) * 16 + lc;
                        float v = fmaxf(acc[mm][tt][r], 0.f);
                        sH[row * HID + (col ^ ((row & 7) << 2))] = pack_split(v);
                    }
            __syncthreads();

            // ---- GEMM2: h2 = relu(h1 @ W2 + b2), K=256, N=256
            gemm_layer<8, 16, 2, HID * 4>(sH, ws + W2H, ws + W2L, sB2, wn, lane, acc);
            __syncthreads();                      // all h1 reads done
            #pragma unroll
            for (int mm = 0; mm < 3; ++mm)
                #pragma unroll
                for (int tt = 0; tt < 2; ++tt)
                    #pragma unroll
                    for (int r = 0; r < 4; ++r) {
                        int row = mm * 16 + lr * 4 + r;
                        int col = (wn * 2 + tt) * 16 + lc;
                        float v = fmaxf(acc[mm][tt][r], 0.f);
                        sH[row * HID + (col ^ ((row & 7) << 2))] = pack_split(v);
                    }
            __syncthreads();

            // ---- GEMM3: k = h2 @ W3 + b3, K=256, N=128(pad; cols>=72 all 0)
            f32x4 acc3[3][1];
            gemm_layer<8, 8, 1, HID * 4>(sH, ws + W3H, ws + W3L, sB3, wn, lane, acc3);

            // ---- RK4 owner update (each thread owns its C elements)
            #pragma unroll
            for (int mm = 0; mm < 3; ++mm)
                #pragma unroll
                for (int r = 0; r < 4; ++r) {
                    int row = mm * 16 + lr * 4 + r;
                    int zi  = row * KP1 + (d ^ ((row & 7) << 2));
                    float C = acc3[mm][0][r];
                    float y = Y[mm][r];
                    if (j == 0) {
                        float z = y + (dt * (1.f / 3.f)) * C;
                        if (d < KP1) sZ[zi] = pack_split(z);
                    } else if (j == 1) {
                        float z2 = 0.f;
                        if (d < KP1) z2 = unpack_pair(sZ[zi]);
                        St[mm][r] = z2;
                        float z = 2.f * y - z2 + dt * C;
                        if (d < KP1) sZ[zi] = pack_split(z);
                    } else if (j == 2) {
                        float z3 = 0.f;
                        if (d < KP1) z3 = unpack_pair(sZ[zi]);
                        float z2 = St[mm][r];
                        float z = 2.f * z2 - z3 + dt * C;
                        if (d < KP1) sZ[zi] = pack_split(z);
                        St[mm][r] = 6.f * z2 + 3.f * z3 - 9.f * y + 3.f * dt * C;
                    } else {
                        float yn = y + (St[mm][r] + dt * C) * 0.125f;
                        Y[mm][r] = yn;
                        if (step < 3 && d < KP1) sZ[zi] = pack_split(yn);
                    }
                }
            __syncthreads();
        }
    }

    // ---- outputs: action = clip(y[15:27],±1), force = clip(y[27:36],±2)
    #pragma unroll
    for (int mm = 0; mm < 3; ++mm)
        #pragma unroll
        for (int r = 0; r < 4; ++r) {
            int m = m0 + mm * 16 + lr * 4 + r;
            if (m >= Bn) continue;
            float v = Y[mm][r];
            if (d >= IN_DIM && d < IN_DIM + 12)
                out[m * 12 + (d - IN_DIM)] = fminf(fmaxf(v, -1.f), 1.f);
            else if (d >= IN_DIM + 12 && d < CD)
                out[Bn * 12 + m * 9 + (d - IN_DIM - 12)] = fminf(fmaxf(v, -2.f), 2.f);
        }
}

extern "C" void kernel_launch(void* const* d_in, const int* in_sizes, int n_in,
                              void* d_out, int out_size, void* d_ws, size_t ws_size,
                              hipStream_t stream) {
    const float* x  = (const float*)d_in[0];
    const float* W1 = (const float*)d_in[1];
    const float* b1 = (const float*)d_in[2];
    const float* W2 = (const float*)d_in[3];
    const float* b2 = (const float*)d_in[4];
    const float* W3 = (const float*)d_in[5];
    const float* b3 = (const float*)d_in[6];
    int Bn = in_sizes[0] / IN_DIM;
    int4* ws = (int4*)d_ws;   // needs 480 KB

    hipLaunchKernelGGL(prep_pack, dim3(60), dim3(256), 0, stream, W1, W2, W3, ws);
    int grid = (Bn + MT - 1) / MT;
    hipLaunchKernelGGL(ode_fused, dim3(grid), dim3(NTHR), 0, stream,
                       x, b1, b2, b3, ws, (float*)d_out, Bn);
}